// Round 6
// baseline (185.684 us; speedup 1.0000x reference)
//
#include <hip/hip_runtime.h>
#include <hip/hip_bf16.h>

// ---------------------------------------------------------------------------
// QLayer: per-type 2-layer MLP.
//   h   = relu(x_t @ W1_t + b1_t)       [16384x512]@[512x1024]   (x4 types)
//   out = h @ W2_t + b2_t, padded to 128 cols                    (x4 types)
// Round 6: round-5 structure WITHOUT setprio / in-loop sched_barrier fences.
// Theory: those fences forced read-burst -> MFMA-burst serialization (tile
// time ~= sum of LDS + MFMA + staging instead of max). Let the compiler
// emit counted lgkmcnt interleave (m97 behavior). One barrier per K-tile.
// ---------------------------------------------------------------------------

typedef __attribute__((ext_vector_type(8))) short short8;
typedef __attribute__((ext_vector_type(4))) float f32x4;

#define NT 4
#define NNODE 16384
#define DIN 512
#define DH 1024
#define MAXO 128

static __device__ __forceinline__ ushort f2bf(float f) {
    __hip_bfloat16 h = __float2bfloat16(f);
    return *reinterpret_cast<ushort*>(&h);
}

#define GLD(gsrc, ldst)                                                        \
    __builtin_amdgcn_global_load_lds(                                          \
        (const __attribute__((address_space(1))) void*)(gsrc),                 \
        (__attribute__((address_space(3))) void*)(ldst), 16, 0, 0)

// --- x fp32 -> bf16, [4][16384][512] flat ---------------------------------
__global__ __launch_bounds__(256) void cvt_x_kernel(
    const float* __restrict__ x0, const float* __restrict__ x1,
    const float* __restrict__ x2, const float* __restrict__ x3,
    ushort* __restrict__ out) {
    const int i = blockIdx.x * 256 + threadIdx.x;     // 8-float chunk id
    const int per_t = (NNODE * DIN) / 8;              // 2^20 chunks per type
    const int t = i >> 20;
    const int loc = i & (per_t - 1);
    const float* x = (t == 0) ? x0 : (t == 1) ? x1 : (t == 2) ? x2 : x3;
    const float4* xv = reinterpret_cast<const float4*>(x) + (size_t)loc * 2;
    float4 a = xv[0], b = xv[1];
    union { short8 v; ushort u[8]; } r;
    float f[8] = {a.x, a.y, a.z, a.w, b.x, b.y, b.z, b.w};
#pragma unroll
    for (int j = 0; j < 8; ++j) r.u[j] = f2bf(f[j]);
    reinterpret_cast<short8*>(out)[i] = r.v;
}

// --- weight transpose+convert: in fp32 [R][Cin] -> out bf16 [Cout][R] ------
__global__ __launch_bounds__(256) void cvt_w_t_kernel(
    const float* __restrict__ in, ushort* __restrict__ out,
    int R, int Cin, size_t in_tstride, size_t out_tstride) {
    __shared__ float tile[32][33];
    const int t = blockIdx.z;
    in += (size_t)t * in_tstride;
    out += (size_t)t * out_tstride;
    const int c0 = blockIdx.x * 32, r0 = blockIdx.y * 32;
    const int cx = threadIdx.x & 31;
    const int ry = threadIdx.x >> 5;   // 0..7
#pragma unroll
    for (int j = 0; j < 4; ++j) {
        int rr = ry + j * 8;
        int c = c0 + cx;
        tile[rr][cx] = (c < Cin) ? in[(size_t)(r0 + rr) * Cin + c] : 0.0f;
    }
    __syncthreads();
#pragma unroll
    for (int j = 0; j < 4; ++j) {
        int cc = ry + j * 8;
        out[(size_t)(c0 + cc) * R + r0 + cx] = f2bf(tile[cx][cc]);
    }
}

// --- b2 pad to [4][128] fp32 ----------------------------------------------
__global__ void pad_b2_kernel(const float* __restrict__ b0, const float* __restrict__ b1,
                              const float* __restrict__ b2, const float* __restrict__ b3,
                              float* __restrict__ out) {
    const int i = threadIdx.x;            // 0..511
    const int t = i >> 7, n = i & 127;
    const int sz[4] = {128, 96, 64, 32};
    const float* b = (t == 0) ? b0 : (t == 1) ? b1 : (t == 2) ? b2 : b3;
    out[i] = (n < sz[t]) ? b[n] : 0.0f;
}

// ---------------------------------------------------------------------------
// 1-barrier-per-tile 256-tile bf16 GEMM: C = A[M][K] * BT[N][K]^T + bias
// BM=256, BN in {256,128}, BK=64, 512 threads = 8 waves (WM=2, WN=4).
// Wave tile 128 x (BN/4). LDS: dbuf x (A 32KB + B), XOR-swizzle both sides:
// byte(row,col16) = row*128 + ((col16*16) ^ ((row&7)<<4)).
//
// Per K-tile i:
//   issue GLDs for tile i+1 -> other buffer      (A 4 + B 4|2 per thread)
//   for kkk in {0,1}: { read frags (NF B + 8 A, b128); MFMA 8*NF }
//     -- NO fences: compiler interleaves MFMA with ds_reads (counted lgkmcnt)
//   s_waitcnt vmcnt(0); s_barrier   // single publication point per tile
// MFMA operands swapped: D-row dim = n -> lane holds 4 consecutive n
// => vectorized epilogue (uint2 bf16 / float4 f32 stores).
// ---------------------------------------------------------------------------
template <int BN, bool RELU, bool OUTBF16>
__global__ __launch_bounds__(512, 1) void gemm1b(
    const ushort* __restrict__ Abase, const ushort* __restrict__ Bbase,
    const float* __restrict__ biasbase, void* __restrict__ Cbase,
    int N, int K, int MT,
    size_t strideA, size_t strideB, size_t strideBias, size_t strideC) {
    constexpr int NF = BN / 64;            // N-frags per wave (4 or 2)
    constexpr int NBC = BN * 8 / 512;      // B chunks per thread (4 or 2)
    constexpr int ABYTES = 256 * 64 * 2;   // 32 KB
    constexpr int BBYTES = BN * 64 * 2;    // 32 or 16 KB
    constexpr int BUF = ABYTES + BBYTES;
    __shared__ char lds[2 * BUF];

    // XCD-bijective block swizzle (grid % 8 == 0 by construction)
    const int cpx = gridDim.x >> 3;
    const int g = blockIdx.x;
    const int wg = (g & 7) * cpx + (g >> 3);
    const int NTL = N / BN;
    const int t = wg / (MT * NTL);
    const int rmn = wg % (MT * NTL);
    const int m0 = (rmn / NTL) * 256;
    const int n0 = (rmn % NTL) * BN;

    const ushort* A = Abase + (size_t)t * strideA;
    const ushort* Bp = Bbase + (size_t)t * strideB;
    const float* bias = biasbase + (size_t)t * strideBias;

    const int tid = threadIdx.x;
    const int lane = tid & 63;
    const int w = tid >> 6;
    const int wm = w >> 2, wn = w & 3;     // WM=2, WN=4
    const int lrow = lane & 15, lgrp = lane >> 4;

    // --- staging addresses (src col pre-swizzled, LDS dst linear) ----------
    const ushort* asrc[4];
    int adst[4];
#pragma unroll
    for (int j = 0; j < 4; ++j) {
        const int c = j * 512 + tid;           // chunk 0..2047
        const int r = c >> 3;                  // A row 0..255
        const int cb = ((c & 7) * 16) ^ ((r & 7) << 4);
        asrc[j] = A + (size_t)(m0 + r) * K + (cb >> 1);
        adst[j] = c * 16;
    }
    const ushort* bsrc[NBC];
    int bdst[NBC];
#pragma unroll
    for (int j = 0; j < NBC; ++j) {
        const int c = j * 512 + tid;           // chunk 0..BN*8-1
        const int r = c >> 3;                  // B row 0..BN-1
        const int cb = ((c & 7) * 16) ^ ((r & 7) << 4);
        bsrc[j] = Bp + (size_t)(n0 + r) * K + (cb >> 1);
        bdst[j] = ABYTES + c * 16;
    }

    f32x4 acc[8][NF] = {};
    const int NK = K / 64;

    // --- prologue: stage tile 0 into buf 0 ---------------------------------
#pragma unroll
    for (int j = 0; j < 4; ++j) GLD(asrc[j], lds + adst[j]);
#pragma unroll
    for (int j = 0; j < NBC; ++j) GLD(bsrc[j], lds + bdst[j]);
    asm volatile("s_waitcnt vmcnt(0)" ::: "memory");
    __builtin_amdgcn_s_barrier();
    asm volatile("" ::: "memory");

    for (int i = 0; i < NK; ++i) {
        const char* cu_ = lds + (i & 1) * BUF;
        char* nx_ = lds + ((i + 1) & 1) * BUF;
        const int ktn = (i + 1) * 64;
        const bool st = (i + 1 < NK);

        if (st) {
#pragma unroll
            for (int j = 0; j < 4; ++j) GLD(asrc[j] + ktn, nx_ + adst[j]);
#pragma unroll
            for (int j = 0; j < NBC; ++j) GLD(bsrc[j] + ktn, nx_ + bdst[j]);
        }

#pragma unroll
        for (int kkk = 0; kkk < 2; ++kkk) {
            short8 bfr[NF], af[8];
#pragma unroll
            for (int ni = 0; ni < NF; ++ni) {
                const int br = wn * (NF * 16) + ni * 16 + lrow;
                const int kb = (kkk * 64 + lgrp * 16) ^ ((br & 7) << 4);
                bfr[ni] = *(const short8*)(cu_ + ABYTES + br * 128 + kb);
            }
#pragma unroll
            for (int ml = 0; ml < 8; ++ml) {
                const int ar = wm * 128 + ml * 16 + lrow;
                const int kb = (kkk * 64 + lgrp * 16) ^ ((ar & 7) << 4);
                af[ml] = *(const short8*)(cu_ + ar * 128 + kb);
            }
            // no setprio / no sched_barrier: let the scheduler interleave
            // these MFMAs with the ds_reads above via counted lgkmcnt.
#pragma unroll
            for (int ml = 0; ml < 8; ++ml)
#pragma unroll
                for (int ni = 0; ni < NF; ++ni)
                    acc[ml][ni] = __builtin_amdgcn_mfma_f32_16x16x32_bf16(
                        bfr[ni], af[ml], acc[ml][ni], 0, 0, 0);
        }

        if (st) {
            // publication: tile i+1 fully landed (loads issued ~1 tile ago)
            asm volatile("s_waitcnt vmcnt(0)" ::: "memory");
            __builtin_amdgcn_s_barrier();
            asm volatile("" ::: "memory");
        }
    }

    // --- epilogue (swapped operands): lane holds 4 consecutive n at reg r --
    // m = wmoff + mi*16 + lrow ; n = wnoff + ni*16 + lgrp*4 + r
    const int wnoff = n0 + wn * (NF * 16);
    const int wmoff = m0 + wm * 128;
#pragma unroll
    for (int ni = 0; ni < NF; ++ni) {
        const int ncol = wnoff + ni * 16 + lgrp * 4;
        const float4 bv = *reinterpret_cast<const float4*>(&bias[ncol]);
#pragma unroll
        for (int mi = 0; mi < 8; ++mi) {
            const int row = wmoff + mi * 16 + lrow;
            float v0 = acc[mi][ni][0] + bv.x;
            float v1 = acc[mi][ni][1] + bv.y;
            float v2 = acc[mi][ni][2] + bv.z;
            float v3 = acc[mi][ni][3] + bv.w;
            if (RELU) {
                v0 = fmaxf(v0, 0.0f); v1 = fmaxf(v1, 0.0f);
                v2 = fmaxf(v2, 0.0f); v3 = fmaxf(v3, 0.0f);
            }
            const size_t base = (size_t)t * strideC + (size_t)row * N + ncol;
            if (OUTBF16) {
                uint2 p;
                p.x = (uint)f2bf(v0) | ((uint)f2bf(v1) << 16);
                p.y = (uint)f2bf(v2) | ((uint)f2bf(v3) << 16);
                *reinterpret_cast<uint2*>(&((ushort*)Cbase)[base]) = p;
            } else {
                float4 p = {v0, v1, v2, v3};
                *reinterpret_cast<float4*>(&((float*)Cbase)[base]) = p;
            }
        }
    }
}

extern "C" void kernel_launch(void* const* d_in, const int* in_sizes, int n_in,
                              void* d_out, int out_size, void* d_ws, size_t ws_size,
                              hipStream_t stream) {
    const float* x0 = (const float*)d_in[0];
    const float* x1 = (const float*)d_in[1];
    const float* x2 = (const float*)d_in[2];
    const float* x3 = (const float*)d_in[3];
    // d_in[4] = node_type (unused: nodes are blocked by type already)
    const float* W1 = (const float*)d_in[5];
    const float* b1 = (const float*)d_in[6];
    const float* W2[4] = {(const float*)d_in[7], (const float*)d_in[9],
                          (const float*)d_in[11], (const float*)d_in[13]};
    const float* b2[4] = {(const float*)d_in[8], (const float*)d_in[10],
                          (const float*)d_in[12], (const float*)d_in[14]};

    // workspace layout (bytes):
    //   H    bf16 [4][16384][1024]  134217728
    //   Xbf  bf16 [4][16384][512]    67108864
    //   W1T  bf16 [4][1024][512]      4194304
    //   W2T  bf16 [4][128][1024]      1048576
    //   b2p  f32  [4][128]                2048
    char* ws = (char*)d_ws;
    ushort* H   = (ushort*)ws;
    ushort* Xbf = (ushort*)(ws + 134217728ull);
    ushort* W1T = (ushort*)(ws + 134217728ull + 67108864ull);
    ushort* W2T = (ushort*)(ws + 134217728ull + 67108864ull + 4194304ull);
    float*  b2p = (float*)(ws + 134217728ull + 67108864ull + 4194304ull + 1048576ull);

    // conversions
    cvt_x_kernel<<<16384, 256, 0, stream>>>(x0, x1, x2, x3, Xbf);
    cvt_w_t_kernel<<<dim3(32, 16, 4), 256, 0, stream>>>(
        W1, W1T, DIN, DH, (size_t)DIN * DH, (size_t)DH * DIN);
    const int osz[4] = {128, 96, 64, 32};
    for (int t = 0; t < 4; ++t)
        cvt_w_t_kernel<<<dim3(4, 32, 1), 256, 0, stream>>>(
            W2[t], W2T + (size_t)t * MAXO * DH, DH, osz[t], 0, 0);
    pad_b2_kernel<<<1, 512, 0, stream>>>(b2[0], b2[1], b2[2], b2[3], b2p);

    // layer 1: H = relu(X @ W1 + b1), bf16 out
    // grid: 64 m-tiles x 4 n-tiles x 4 types = 1024
    gemm1b<256, true, true><<<1024, 512, 0, stream>>>(
        Xbf, W1T, b1, H,
        DH, DIN, NNODE / 256,
        (size_t)NNODE * DIN, (size_t)DH * DIN, (size_t)DH, (size_t)NNODE * DH);

    // layer 2: out = H @ W2 + b2 (padded cols exactly 0), fp32 out
    // grid: 64 m-tiles x 1 n-tile x 4 types = 256
    gemm1b<128, false, false><<<256, 512, 0, stream>>>(
        H, W2T, b2p, d_out,
        MAXO, DH, NNODE / 256,
        (size_t)NNODE * DH, (size_t)MAXO * DH, (size_t)MAXO, (size_t)NNODE * MAXO);
}